// Round 8
// baseline (303.721 us; speedup 1.0000x reference)
//
#include <hip/hip_runtime.h>
#include <hip/hip_bf16.h>
#include <cfloat>

// Problem constants (fixed by the reference file)
#define NN 4096
#define DD 256
#define MM 5
#define K_TOT 30       // 20 intra + 10 inter
#define CAND_CAP 64
#define LO_INTRA 26    // need top-21 (incl self) + 5 ranks bf16-rounding slack
#define LO_INTER 15    // need top-10 + 5 ranks slack

typedef __attribute__((ext_vector_type(8))) short bf16x8;
typedef __attribute__((ext_vector_type(4))) float f32x4;

// async global->LDS, 16 B per lane; LDS dest = wave-uniform base + lane*16
__device__ __forceinline__ void async16(const void* g, void* l) {
    __builtin_amdgcn_global_load_lds((__attribute__((address_space(1))) void*)g,
                                     (__attribute__((address_space(3))) void*)l,
                                     16, 0, 0);
}

// sortable 16-bit key of a float after bf16(RNE) rounding (monotone in value)
__device__ __forceinline__ unsigned key16_of_float(float f) {
    unsigned u = __float_as_uint(f);
    unsigned r = ((u + 0x7FFFu + ((u >> 16) & 1u)) >> 16) & 0xFFFFu;
    return (r & 0x8000u) ? (r ^ 0xFFFFu) : (r | 0x8000u);
}

// ---------------------------------------------------------------------------
// Kernel 0: E fp32 -> bf16 (RNE). Selection-only precision; exact ordering
// comes from the fp64 rescore in select_rescore.
// ---------------------------------------------------------------------------
__global__ __launch_bounds__(256) void convert_bf16(const float* __restrict__ E,
                                                    ushort* __restrict__ Eb) {
    const int idx = blockIdx.x * 256 + threadIdx.x;
    const float4 f = ((const float4*)E)[idx];
    ushort4 h;
    {
        __hip_bfloat16 a = __float2bfloat16(f.x); h.x = *(ushort*)&a;
        __hip_bfloat16 b = __float2bfloat16(f.y); h.y = *(ushort*)&b;
        __hip_bfloat16 c = __float2bfloat16(f.z); h.z = *(ushort*)&c;
        __hip_bfloat16 d = __float2bfloat16(f.w); h.w = *(ushort*)&d;
    }
    ((ushort4*)Eb)[idx] = h;
}

// ---------------------------------------------------------------------------
// Kernel 1: sim = Eb @ Eb^T via MFMA bf16 -> bf16 out. 128x128 tile, 4 waves
// (2x2 of 64x64), 16x16x32 MFMA, BK=32. global_load_lds width=16 staging,
// XOR chunk swizzle (2-way max = free). Also zeroes this block's 128x128
// region of the locality output (replaces the serialized 67 MB memset,
// overlapped with compute). Epilogue staged in 4 chunks of 32 rows.
// ---------------------------------------------------------------------------
__global__ __launch_bounds__(256) void gemm_bf16(const ushort* __restrict__ Eb,
                                                 ushort* __restrict__ simb,
                                                 float* __restrict__ locout) {
    __shared__ union {
        struct { ushort A[128 * 32]; ushort B[128 * 32]; } s;  // 8 KB + 8 KB
        ushort stage[32 * 136];                                // 8.7 KB epilogue
    } lds;

    const int t = threadIdx.x;
    const int w = t >> 6, lane = t & 63;
    const int quad = lane >> 4, mr = lane & 15;
    const int rowBase = blockIdx.y * 128, colBase = blockIdx.x * 128;
    const int waveRow = (w & 1) * 64, waveCol = (w >> 1) * 64;

    const int lrow = lane >> 2;              // 0..15 row within 16-row slab
    const int lslot = lane & 3;              // LDS chunk slot
    const int gchunk = lslot ^ ((lrow >> 1) & 3);  // swizzled global chunk

    // zero this block's locality region (fire-and-forget, overlaps K-loop)
    if (locout != nullptr) {
        const float4 z4 = make_float4(0.f, 0.f, 0.f, 0.f);
#pragma unroll
        for (int it = 0; it < 16; ++it) {
            const int idx = t + it * 256;        // 0..4095
            const int row = idx >> 5;            // 0..127
            const int col4 = idx & 31;           // 0..31 (float4 units)
            *(float4*)(locout + (size_t)(rowBase + row) * NN + colBase + col4 * 4) = z4;
        }
    }

    f32x4 acc[4][4];
#pragma unroll
    for (int a = 0; a < 4; ++a)
#pragma unroll
        for (int b = 0; b < 4; ++b) acc[a][b] = (f32x4)(0.0f);

    for (int kc = 0; kc < DD; kc += 32) {
#pragma unroll
        for (int n = 0; n < 2; ++n) {
            const int r = w * 32 + n * 16 + lrow;  // (r>>1)&3 == (lrow>>1)&3
            const ushort* ga = Eb + (size_t)(rowBase + r) * DD + kc + gchunk * 8;
            const ushort* gb = Eb + (size_t)(colBase + r) * DD + kc + gchunk * 8;
            async16(ga, &lds.s.A[(w * 32 + n * 16) * 32]);
            async16(gb, &lds.s.B[(w * 32 + n * 16) * 32]);
        }
        __syncthreads();

        const int swzF = (mr >> 1) & 3;
        bf16x8 af[4], bfr[4];
#pragma unroll
        for (int rt = 0; rt < 4; ++rt)
            af[rt] = *(const bf16x8*)&lds.s.A[(waveRow + rt * 16 + mr) * 32 +
                                              ((quad ^ swzF) * 8)];
#pragma unroll
        for (int ct = 0; ct < 4; ++ct)
            bfr[ct] = *(const bf16x8*)&lds.s.B[(waveCol + ct * 16 + mr) * 32 +
                                               ((quad ^ swzF) * 8)];
#pragma unroll
        for (int rt = 0; rt < 4; ++rt)
#pragma unroll
            for (int ct = 0; ct < 4; ++ct)
                acc[rt][ct] = __builtin_amdgcn_mfma_f32_16x16x32_bf16(
                    af[rt], bfr[ct], acc[rt][ct], 0, 0, 0);
        __syncthreads();
    }

    // epilogue: 4 chunks of 32 tile-rows through the 8.7 KB stage buffer
#pragma unroll
    for (int c = 0; c < 4; ++c) {
        __syncthreads();
        if ((w & 1) == (c >> 1)) {
            const int rtBase = 2 * (c & 1);
#pragma unroll
            for (int r2 = 0; r2 < 2; ++r2) {
                const int rt = rtBase + r2;
#pragma unroll
                for (int ct = 0; ct < 4; ++ct)
#pragma unroll
                    for (int reg = 0; reg < 4; ++reg) {
                        __hip_bfloat16 hb = __float2bfloat16(acc[rt][ct][reg]);
                        const int lr2 = r2 * 16 + quad * 4 + reg;  // 0..31
                        lds.stage[lr2 * 136 + waveCol + ct * 16 + mr] = *(ushort*)&hb;
                    }
            }
        }
        __syncthreads();
#pragma unroll
        for (int it = 0; it < 2; ++it) {
            const int cid = t + it * 256;   // 0..511 (32 rows x 16 int4)
            const int row = cid >> 4;
            const int off = (cid & 15) * 8;
            *(int4*)(simb + (size_t)(rowBase + c * 32 + row) * NN + colBase + off) =
                *(const int4*)&lds.stage[row * 136 + off];
        }
    }
}

// ---------------------------------------------------------------------------
// Kernel 2: one wave per row, HISTOGRAM-FREE count-threshold selection.
// Threshold semantics: any theta with count(key >= theta) in [target, 64]
// captures the exact top-target by bf16 key. Warm-start theta from the known
// sim distribution (enc ~ N(0,1) => sigma = sqrt(D) = 16) verified by one
// atomic-free register count pass (~97% of rows); exact 16-step key-space
// bisection fallback otherwise. Collect ~58 atomics/row. fp64 rescore from
// fp32 E + rank-based ordered output (unchanged; gives exact lax.top_k
// order).
// ---------------------------------------------------------------------------
__global__ __launch_bounds__(256) void select_rescore(const ushort* __restrict__ sim,
                                                      const float* __restrict__ E,
                                                      const int* __restrict__ batch,
                                                      int* __restrict__ knn) {
    __shared__ int candIdxS[4][2][CAND_CAP];
    __shared__ double candValS[4][2][CAND_CAP];
    __shared__ int cntS[4][2];

    const int t = threadIdx.x;
    const int w = t >> 6, lane = t & 63;
    const int i = blockIdx.x * 4 + w;
    const int bi = batch[i];

    if (lane < 2) cntS[w][lane] = 0;

    // ---- load 64 elems/lane: packed sortable keys + inter-mask ----
    // element j = c*512 + lane*8 + e
    unsigned kp[32];
    unsigned long long interm = 0;  // bit (c*8+e) => batch differs (INTER)
    {
        const ushort* sp = sim + (size_t)i * NN + lane * 8;
        const int* bp = batch + lane * 8;
#pragma unroll
        for (int c = 0; c < 8; ++c) {
            const int4 sv = *(const int4*)(sp + c * 512);
            int bb[8];
            *(int4*)&bb[0] = *(const int4*)(bp + c * 512);
            *(int4*)&bb[4] = *(const int4*)(bp + c * 512 + 4);
            const unsigned uu[4] = {(unsigned)sv.x, (unsigned)sv.y,
                                    (unsigned)sv.z, (unsigned)sv.w};
#pragma unroll
            for (int p = 0; p < 4; ++p) {
                const unsigned u = uu[p];
                const unsigned sgn = u & 0x80008000u;
                // per-half monotone transform: pos ^0x8000, neg ^0xFFFF
                kp[c * 4 + p] = u ^ (0x80008000u | ((sgn >> 15) * 0x7FFFu));
                const unsigned m0 = (bb[2 * p] == bi) ? 0u : 1u;
                const unsigned m1 = (bb[2 * p + 1] == bi) ? 0u : 1u;
                interm |= (unsigned long long)m0 << (c * 8 + 2 * p);
                interm |= (unsigned long long)m1 << (c * 8 + 2 * p + 1);
            }
        }
    }

    // packed count of {intra >= K0} (lo16) and {inter >= K1} (hi16)
    auto countBoth = [&](unsigned K0, unsigned K1) -> unsigned {
        unsigned cnt = 0;
#pragma unroll
        for (int r = 0; r < 32; ++r) {
            const unsigned k2 = kp[r];
            const int e = (r >> 2) * 8 + (r & 3) * 2;
            const unsigned m0 = (unsigned)(interm >> e) & 1u;
            const unsigned m1 = (unsigned)(interm >> (e + 1)) & 1u;
            const unsigned k0 = k2 & 0xFFFFu, k1 = k2 >> 16;
            if (k0 >= (m0 ? K1 : K0)) cnt += m0 ? 0x10000u : 1u;
            if (k1 >= (m1 ? K1 : K0)) cnt += m1 ? 0x10000u : 1u;
        }
#pragma unroll
        for (int off = 1; off < 64; off <<= 1) cnt += __shfl_xor(cnt, off);
        return cnt;
    };

    // ---- threshold: warm start (sigma=16) + verify; bisect on failure ----
    unsigned K0 = key16_of_float(1.76f * 16.0f);  // E[cnt_intra] ~ 40 in [26,64]
    unsigned K1 = key16_of_float(2.34f * 16.0f);  // E[cnt_inter] ~ 30 in [15,64]
    {
        const unsigned cnt = countBoth(K0, K1);
        const unsigned c0 = cnt & 0xFFFFu, c1 = cnt >> 16;
        const bool ok0 = (c0 >= LO_INTRA && c0 <= CAND_CAP);
        const bool ok1 = (c1 >= LO_INTER && c1 <= CAND_CAP);
        if (!(ok0 && ok1)) {
            // exact: max t such that count(>= t) >= LO  (monotone in t)
            unsigned L0 = 0, R0 = 0xFFFFu, L1 = 0, R1 = 0xFFFFu;
            for (int it = 0; it < 16; ++it) {
                const unsigned mid0 = (L0 + R0 + 1) >> 1;
                const unsigned mid1 = (L1 + R1 + 1) >> 1;
                const unsigned cc = countBoth(mid0, mid1);
                if ((cc & 0xFFFFu) >= LO_INTRA) L0 = mid0; else R0 = mid0 - 1;
                if ((cc >> 16) >= LO_INTER) L1 = mid1; else R1 = mid1 - 1;
            }
            if (!ok0) K0 = L0;  // cnt ~ LO + tie-multiplicity <= 64 in practice
            if (!ok1) K1 = L1;
        }
    }
    __syncthreads();  // cntS init visible

    // ---- collect candidate indices (~58 atomics per row) ----
#pragma unroll
    for (int r = 0; r < 32; ++r) {
        const unsigned k2 = kp[r];
        const int e = (r >> 2) * 8 + (r & 3) * 2;
        const int j0 = (r >> 2) * 512 + lane * 8 + (r & 3) * 2;
        const unsigned m0 = (unsigned)(interm >> e) & 1u;
        const unsigned m1 = (unsigned)(interm >> (e + 1)) & 1u;
        if ((k2 & 0xFFFFu) >= (m0 ? K1 : K0)) {
            const int pos = atomicAdd(&cntS[w][m0], 1);
            if (pos < CAND_CAP) candIdxS[w][m0][pos] = j0;
        }
        if ((k2 >> 16) >= (m1 ? K1 : K0)) {
            const int pos = atomicAdd(&cntS[w][m1], 1);
            if (pos < CAND_CAP) candIdxS[w][m1][pos] = j0 + 1;
        }
    }
    __syncthreads();

    // ---- fp64 rescore; E[i] row is wave-uniform -> scalar loads ----
    const int c0 = min(cntS[w][0], CAND_CAP);
    const int c1 = min(cntS[w][1], CAND_CAP);
    {
        const int tot = c0 + c1;
        const float* ei = E + (size_t)i * DD;
        for (int base = 0; base < tot; base += 64) {
            const int slot = base + lane;
            if (slot < tot) {
                const int m = (slot < c0) ? 0 : 1;
                const int s = m ? (slot - c0) : slot;
                const int j = candIdxS[w][m][s];
                const float* ej = E + (size_t)j * DD;
                double a0 = 0, a1 = 0, a2 = 0, a3 = 0;
#pragma unroll 8
                for (int k = 0; k < DD; k += 4) {
                    const float4 e4 = *(const float4*)(ej + k);
                    a0 = fma((double)ei[k + 0], (double)e4.x, a0);
                    a1 = fma((double)ei[k + 1], (double)e4.y, a1);
                    a2 = fma((double)ei[k + 2], (double)e4.z, a2);
                    a3 = fma((double)ei[k + 3], (double)e4.w, a3);
                }
                candValS[w][m][s] = (a0 + a1) + (a2 + a3);
            }
        }
    }
    __syncthreads();

    // ---- rank-based ordered output (ties: lower index first) ----
    if (lane < c0) {
        const double v = candValS[w][0][lane];
        const int idx = candIdxS[w][0][lane];
        int r = 0;
        for (int s = 0; s < c0; ++s) {
            const double o = candValS[w][0][s];
            const int oi = candIdxS[w][0][s];
            r += (o > v) || (o == v && oi < idx);
        }
        if (r >= 1 && r <= 20) knn[i * K_TOT + r - 1] = idx;  // rank0 dropped
    }
    if (lane < c1) {
        const double v = candValS[w][1][lane];
        const int idx = candIdxS[w][1][lane];
        int r = 0;
        for (int s = 0; s < c1; ++s) {
            const double o = candValS[w][1][s];
            const int oi = candIdxS[w][1][s];
            r += (o > v) || (o == v && oi < idx);
        }
        if (r < 10) knn[i * K_TOT + 20 + r] = idx;
    }
}

// ---------------------------------------------------------------------------
// Kernel 3: mutuality + sparse locality scatter + all_close.
// ---------------------------------------------------------------------------
__global__ __launch_bounds__(256) void finalize_k(const int* __restrict__ knn,
                                                  const float* __restrict__ adj,
                                                  const int* __restrict__ cl,
                                                  float* __restrict__ out) {
    const int gid = blockIdx.x * 256 + threadIdx.x;
    if (gid >= NN * K_TOT) return;
    const int i = gid / K_TOT;
    const int j = knn[gid];

    bool mutual = false;
#pragma unroll
    for (int s = 0; s < K_TOT; ++s) mutual |= (knn[j * K_TOT + s] == i);

    if (mutual) out[(size_t)i * NN + j] = adj[(size_t)i * NN + j];

    bool ac = mutual;
    if (!ac) {
        bool alleq = true;
#pragma unroll
        for (int m = 0; m < MM; ++m) alleq &= (cl[m * NN + i] == cl[m * NN + j]);
        ac = alleq;
    }
    out[(size_t)NN * NN + gid] = ac ? 1.0f : 0.0f;
}

// ---------------------------------------------------------------------------
extern "C" void kernel_launch(void* const* d_in, const int* in_sizes, int n_in,
                              void* d_out, int out_size, void* d_ws, size_t ws_size,
                              hipStream_t stream) {
    const float* adj = (const float*)d_in[0];
    const float* enc = (const float*)d_in[1];
    const int* batch = (const int*)d_in[2];
    const int* cl = (const int*)d_in[3];
    float* out = (float*)d_out;

    const size_t simB = (size_t)NN * NN * sizeof(ushort);   // 33.6 MB
    const size_t ebB = (size_t)NN * DD * sizeof(ushort);    // 2.1 MB
    const size_t knnB = (size_t)NN * K_TOT * sizeof(int);   // 0.49 MB

    const dim3 gGrid(NN / 128, NN / 128);

    if (ws_size >= simB + ebB + knnB) {
        ushort* simb = (ushort*)d_ws;
        ushort* Eb = (ushort*)((char*)d_ws + simB);
        int* knn = (int*)((char*)d_ws + simB + ebB);
        convert_bf16<<<NN * DD / 4 / 256, 256, 0, stream>>>(enc, Eb);
        gemm_bf16<<<gGrid, 256, 0, stream>>>(Eb, simb, out);  // also zeroes locality
        select_rescore<<<NN / 4, 256, 0, stream>>>(simb, enc, batch, knn);
        finalize_k<<<(NN * K_TOT + 255) / 256, 256, 0, stream>>>(knn, adj, cl, out);
    } else {
        // fallback: stage bf16 sims in the locality region of d_out, memset after
        ushort* simb = (ushort*)d_out;
        ushort* Eb = (ushort*)d_ws;
        int* knn = (int*)((char*)d_ws + ebB);
        convert_bf16<<<NN * DD / 4 / 256, 256, 0, stream>>>(enc, Eb);
        gemm_bf16<<<gGrid, 256, 0, stream>>>(Eb, simb, nullptr);
        select_rescore<<<NN / 4, 256, 0, stream>>>(simb, enc, batch, knn);
        hipMemsetAsync(d_out, 0, (size_t)NN * NN * sizeof(float), stream);
        finalize_k<<<(NN * K_TOT + 255) / 256, 256, 0, stream>>>(knn, adj, cl, out);
    }
}